// Round 7
// baseline (137.663 us; speedup 1.0000x reference)
//
#include <hip/hip_runtime.h>
#include <hip/hip_cooperative_groups.h>

// Causal linear attention (ELU+1), fully fused single cooperative kernel.
// B=2, L=4096, dk=dv=128 fp32. Chunk C=128, grid (NC=32, B=2) = 64 blocks,
// 512 threads, ~140KB LDS -> 1 block/CU, 64 co-resident (cooperative).
// Flow: stage chunk -> S_c^T+ksum (MFMA) -> publish agg -> grid.sync ->
// register prefix-sum of j<c aggs -> A=phiQ phiK^T -> mask -> AmV (+ones z)
// -> prefix->LDS -> phiQ S_prev (+kprev z) -> out/z.
// R6 bug: ksum guard used wc==0 (4 waves, all colb=0) -> aggK[64..127] never
// written (stale poison) -> z half-sized -> absmax 0.30.  Fix: ksum needs
// COLUMN coverage -> doK=((w&3)==0) (waves 0,4: colb 0,64); z needs ROW
// coverage -> doZ=(wc==0) (waves 0-3: rowb 0..96).  Distinct guards.
// Harness floor ~46us (256MB ws poison fill + input restore).

#define EPS 1e-6f

constexpr int Bc = 2;
constexpr int L  = 4096;
constexpr int D  = 128;
constexpr int C  = 128;
constexpr int NC = L / C;   // 32
constexpr int P  = 136;     // LDS row pitch (bf16), rows 16B-aligned

typedef short sh8 __attribute__((ext_vector_type(8)));
typedef float f4  __attribute__((ext_vector_type(4)));

__device__ __forceinline__ float phi(float x) {
    return x > 0.0f ? x + 1.0f : __expf(x);
}
__device__ __forceinline__ unsigned short f2bf(float f) {
    unsigned u = __float_as_uint(f);
    return (unsigned short)((u + 0x7FFFu + ((u >> 16) & 1u)) >> 16);  // RNE
}
__device__ __forceinline__ unsigned packbf(float a, float b) {
    return (unsigned)f2bf(a) | ((unsigned)f2bf(b) << 16);
}
__device__ __forceinline__ sh8 splat1() {
    sh8 s;
#pragma unroll
    for (int j = 0; j < 8; ++j) s[j] = (short)0x3F80;
    return s;
}

__global__ __launch_bounds__(512) void k_fused(
    const float* __restrict__ Q, const float* __restrict__ K,
    const float* __restrict__ V, unsigned short* __restrict__ aggS,
    float* __restrict__ aggK, float* __restrict__ Out) {
    const int c = blockIdx.x, b = blockIdx.y;
    const int tid = threadIdx.x;
    __shared__ __align__(16) unsigned short sQ[128 * P];   // phiQ [l][i]
    __shared__ __align__(16) unsigned short sK[128 * P];   // phiK [j][i]
    __shared__ __align__(16) unsigned short sKT[128 * P];  // phiK^T [i][l] -> sAm
    __shared__ __align__(16) unsigned short sVT[128 * P];  // V^T [v][l]    -> sS
    __shared__ float sKp[128];
    __shared__ float sZ[128];
    unsigned short* sAm = sKT;   // masked A [l][j], alias (sKT dead post-phase1)
    unsigned short* sS  = sVT;   // S_prev^T [v][i], alias (sVT dead post-GEMM3)

    const size_t base = ((size_t)b * L + (size_t)c * C) * D;

    // ---- Phase 0: stage chunk. Coalesced float4 reads; row-major sQ/sK;
    // swizzled transpose for sKT/sVT: elem (l,row) at col ((l>>3 + row>>2)&15)*8
    // + (l&7); k-groups of 8 stay contiguous -> frag reads stay sh8. ----
    for (int k = 0; k < 8; ++k) {
        int fi = tid + 512 * k;               // 4096 float4 per tensor
        int l = fi >> 5, i4 = fi & 31;
        float4 qd = *(const float4*)(Q + base + (size_t)l * D + i4 * 4);
        float4 kd = *(const float4*)(K + base + (size_t)l * D + i4 * 4);
        float4 vd = *(const float4*)(V + base + (size_t)l * D + i4 * 4);
        uint2 pq; pq.x = packbf(phi(qd.x), phi(qd.y)); pq.y = packbf(phi(qd.z), phi(qd.w));
        *(uint2*)(sQ + l * P + i4 * 4) = pq;
        unsigned short k0 = f2bf(phi(kd.x)), k1 = f2bf(phi(kd.y));
        unsigned short k2 = f2bf(phi(kd.z)), k3 = f2bf(phi(kd.w));
        uint2 pk; pk.x = (unsigned)k0 | ((unsigned)k1 << 16); pk.y = (unsigned)k2 | ((unsigned)k3 << 16);
        *(uint2*)(sK + l * P + i4 * 4) = pk;
        int blk = (((l >> 3) + i4) & 15) * 8 + (l & 7);
        sKT[(i4 * 4 + 0) * P + blk] = k0;
        sKT[(i4 * 4 + 1) * P + blk] = k1;
        sKT[(i4 * 4 + 2) * P + blk] = k2;
        sKT[(i4 * 4 + 3) * P + blk] = k3;
        sVT[(i4 * 4 + 0) * P + blk] = f2bf(vd.x);
        sVT[(i4 * 4 + 1) * P + blk] = f2bf(vd.y);
        sVT[(i4 * 4 + 2) * P + blk] = f2bf(vd.z);
        sVT[(i4 * 4 + 3) * P + blk] = f2bf(vd.w);
    }
    __syncthreads();

    const int w = tid >> 6, lane = tid & 63;
    const int r = lane & 15, q = lane >> 4;
    const int rowb = (w & 3) * 32;          // 32-row group (rows/v/l)
    const int wc = w >> 2, colb = wc * 64;  // 64-col group (cols/i/j/v)
    const bool doK = ((w & 3) == 0);        // ksum: column coverage (w=0: i<64, w=4: i>=64)
    const bool doZ = (wc == 0);             // z: row coverage (waves 0-3: all 128 rows)

    // ---- Phase 1: S_c^T[v][i] = sum_l V^T[v][l] phiK^T[i][l]; ksum via
    // ones-A (colsum). Publish bf16 aggregate. ----
    {
        f4 s1[8], kz[4];
#pragma unroll
        for (int f = 0; f < 8; ++f) s1[f] = {0.f, 0.f, 0.f, 0.f};
#pragma unroll
        for (int f = 0; f < 4; ++f) kz[f] = {0.f, 0.f, 0.f, 0.f};
        const sh8 ones = splat1();
#pragma unroll
        for (int ks = 0; ks < 4; ++ks) {
            int kq = ks * 4 + q;
            int vr0 = rowb + r, vr1 = rowb + 16 + r;
            sh8 a0 = *(const sh8*)(sVT + vr0 * P + ((kq + (vr0 >> 2)) & 15) * 8);
            sh8 a1 = *(const sh8*)(sVT + vr1 * P + ((kq + (vr1 >> 2)) & 15) * 8);
#pragma unroll
            for (int f = 0; f < 4; ++f) {
                int ir = colb + f * 16 + r;
                sh8 bk = *(const sh8*)(sKT + ir * P + ((kq + (ir >> 2)) & 15) * 8);
                s1[f]     = __builtin_amdgcn_mfma_f32_16x16x32_bf16(a0, bk, s1[f], 0, 0, 0);
                s1[4 + f] = __builtin_amdgcn_mfma_f32_16x16x32_bf16(a1, bk, s1[4 + f], 0, 0, 0);
                if (doK) kz[f] = __builtin_amdgcn_mfma_f32_16x16x32_bf16(ones, bk, kz[f], 0, 0, 0);
            }
        }
        unsigned short* ag = aggS + ((size_t)(b * NC + c)) * D * D;
#pragma unroll
        for (int fr = 0; fr < 2; ++fr)
#pragma unroll
            for (int f = 0; f < 4; ++f) {
                int i = colb + f * 16 + r;
#pragma unroll
                for (int e = 0; e < 4; ++e) {
                    int v = rowb + fr * 16 + q * 4 + e;
                    ag[(size_t)v * D + i] = f2bf(s1[fr * 4 + f][e]);
                }
            }
        if (doK && q == 0) {
#pragma unroll
            for (int f = 0; f < 4; ++f)
                aggK[((size_t)(b * NC + c)) * D + colb + f * 16 + r] = kz[f][0];
        }
    }
    __threadfence();
    cooperative_groups::this_grid().sync();

    // ---- Phase 2: register prefix sum of aggregates j < c.  Thread t owns
    // S^T elems [t*32, t*32+32) (v=t>>2, i0=(t&3)*32).  kprev on tid<128. ----
    float pr[32];
#pragma unroll
    for (int t = 0; t < 32; ++t) pr[t] = 0.f;
    if (tid < 128) {
        float s = 0.f;
        for (int j = 0; j < c; ++j) s += aggK[((size_t)(b * NC + j)) * D + tid];
        sKp[tid] = s;
    }
    {
        const unsigned short* ab = aggS + (size_t)b * NC * D * D;
        for (int j = 0; j < c; ++j) {
            const uint4* p = (const uint4*)(ab + (size_t)j * D * D) + tid * 4;
            uint4 dd[4] = {p[0], p[1], p[2], p[3]};
#pragma unroll
            for (int a = 0; a < 4; ++a) {
                unsigned uu[4] = {dd[a].x, dd[a].y, dd[a].z, dd[a].w};
#pragma unroll
                for (int u = 0; u < 4; ++u) {
                    int e0 = a * 8 + u * 2;
                    pr[e0]     += __uint_as_float(uu[u] << 16);
                    pr[e0 + 1] += __uint_as_float(uu[u] & 0xFFFF0000u);
                }
            }
        }
    }

    // ---- Phase 3: GEMM2 A = phiQ phiK^T; causal mask -> sAm (bf16). ----
    {
        f4 a2[8];
#pragma unroll
        for (int f = 0; f < 8; ++f) a2[f] = {0.f, 0.f, 0.f, 0.f};
#pragma unroll
        for (int ks = 0; ks < 4; ++ks) {
            sh8 aq0 = *(const sh8*)(sQ + (rowb + r) * P + ks * 32 + q * 8);
            sh8 aq1 = *(const sh8*)(sQ + (rowb + 16 + r) * P + ks * 32 + q * 8);
#pragma unroll
            for (int f = 0; f < 4; ++f) {
                sh8 bk = *(const sh8*)(sK + (colb + f * 16 + r) * P + ks * 32 + q * 8);
                a2[f]     = __builtin_amdgcn_mfma_f32_16x16x32_bf16(aq0, bk, a2[f], 0, 0, 0);
                a2[4 + f] = __builtin_amdgcn_mfma_f32_16x16x32_bf16(aq1, bk, a2[4 + f], 0, 0, 0);
            }
        }
#pragma unroll
        for (int fr = 0; fr < 2; ++fr)
#pragma unroll
            for (int f = 0; f < 4; ++f) {
                int j = colb + f * 16 + r;
#pragma unroll
                for (int e = 0; e < 4; ++e) {
                    int l = rowb + fr * 16 + q * 4 + e;
                    sAm[l * P + j] = f2bf((j <= l) ? a2[fr * 4 + f][e] : 0.f);
                }
            }
    }
    __syncthreads();                      // S2: sAm + sKp ready

    // ---- Phase 4: GEMM3 acc = Am @ V (+ rowsum z via ones-B). ----
    f4 acc[8], z3[2];
#pragma unroll
    for (int f = 0; f < 8; ++f) acc[f] = {0.f, 0.f, 0.f, 0.f};
    z3[0] = {0.f, 0.f, 0.f, 0.f}; z3[1] = {0.f, 0.f, 0.f, 0.f};
    {
        const sh8 ones = splat1();
#pragma unroll
        for (int ks = 0; ks < 4; ++ks) {
            int kq = ks * 4 + q;
            sh8 am0 = *(const sh8*)(sAm + (rowb + r) * P + ks * 32 + q * 8);
            sh8 am1 = *(const sh8*)(sAm + (rowb + 16 + r) * P + ks * 32 + q * 8);
#pragma unroll
            for (int f = 0; f < 4; ++f) {
                int vr = colb + f * 16 + r;
                sh8 bv = *(const sh8*)(sVT + vr * P + ((kq + (vr >> 2)) & 15) * 8);
                acc[f]     = __builtin_amdgcn_mfma_f32_16x16x32_bf16(am0, bv, acc[f], 0, 0, 0);
                acc[4 + f] = __builtin_amdgcn_mfma_f32_16x16x32_bf16(am1, bv, acc[4 + f], 0, 0, 0);
            }
            if (doZ) {
                z3[0] = __builtin_amdgcn_mfma_f32_16x16x32_bf16(am0, ones, z3[0], 0, 0, 0);
                z3[1] = __builtin_amdgcn_mfma_f32_16x16x32_bf16(am1, ones, z3[1], 0, 0, 0);
            }
        }
    }
    __syncthreads();                      // S3: sVT reads done

    // ---- Phase 5: spill register prefix -> sS (row-major [v][i]). ----
    {
        int vr = tid >> 2, i0 = (tid & 3) * 32;
        unsigned short* dst = sS + vr * P + i0;
#pragma unroll
        for (int a = 0; a < 4; ++a) {
            uint4 o;
            o.x = packbf(pr[a * 8 + 0], pr[a * 8 + 1]);
            o.y = packbf(pr[a * 8 + 2], pr[a * 8 + 3]);
            o.z = packbf(pr[a * 8 + 4], pr[a * 8 + 5]);
            o.w = packbf(pr[a * 8 + 6], pr[a * 8 + 7]);
            *(uint4*)(dst + a * 8) = o;
        }
    }
    __syncthreads();                      // S4: sS ready

    // ---- Phase 6: GEMM4 acc += phiQ @ S_prev (+ kprev z). ----
    {
        sh8 bzk[4];
        if (doZ) {
#pragma unroll
            for (int ks = 0; ks < 4; ++ks) {
                float4 f0 = *(const float4*)(sKp + ks * 32 + q * 8);
                float4 f1 = *(const float4*)(sKp + ks * 32 + q * 8 + 4);
                sh8 t;
                t[0] = (short)f2bf(f0.x); t[1] = (short)f2bf(f0.y);
                t[2] = (short)f2bf(f0.z); t[3] = (short)f2bf(f0.w);
                t[4] = (short)f2bf(f1.x); t[5] = (short)f2bf(f1.y);
                t[6] = (short)f2bf(f1.z); t[7] = (short)f2bf(f1.w);
                bzk[ks] = t;
            }
        }
#pragma unroll
        for (int ks = 0; ks < 4; ++ks) {
            sh8 aq0 = *(const sh8*)(sQ + (rowb + r) * P + ks * 32 + q * 8);
            sh8 aq1 = *(const sh8*)(sQ + (rowb + 16 + r) * P + ks * 32 + q * 8);
#pragma unroll
            for (int f = 0; f < 4; ++f) {
                sh8 bs = *(const sh8*)(sS + (colb + f * 16 + r) * P + ks * 32 + q * 8);
                acc[f]     = __builtin_amdgcn_mfma_f32_16x16x32_bf16(aq0, bs, acc[f], 0, 0, 0);
                acc[4 + f] = __builtin_amdgcn_mfma_f32_16x16x32_bf16(aq1, bs, acc[4 + f], 0, 0, 0);
            }
            if (doZ) {
                z3[0] = __builtin_amdgcn_mfma_f32_16x16x32_bf16(aq0, bzk[ks], z3[0], 0, 0, 0);
                z3[1] = __builtin_amdgcn_mfma_f32_16x16x32_bf16(aq1, bzk[ks], z3[1], 0, 0, 0);
            }
        }
        if (doZ && r == 0) {
#pragma unroll
            for (int fr = 0; fr < 2; ++fr)
#pragma unroll
                for (int e = 0; e < 4; ++e)
                    sZ[rowb + fr * 16 + q * 4 + e] = z3[fr][e] + EPS;
        }
    }
    __syncthreads();                      // S5: sZ ready

    // ---- Phase 7: normalize + store. ----
#pragma unroll
    for (int fr = 0; fr < 2; ++fr)
#pragma unroll
        for (int f = 0; f < 4; ++f) {
            int v = colb + f * 16 + r;
#pragma unroll
            for (int e = 0; e < 4; ++e) {
                int l = rowb + fr * 16 + q * 4 + e;
                Out[base + (size_t)l * D + v] = acc[fr * 4 + f][e] / sZ[l];
            }
        }
}

extern "C" void kernel_launch(void* const* d_in, const int* in_sizes, int n_in,
                              void* d_out, int out_size, void* d_ws, size_t ws_size,
                              hipStream_t stream) {
    const float* Q = (const float*)d_in[0];
    const float* K = (const float*)d_in[1];
    const float* V = (const float*)d_in[2];
    float* Out = (float*)d_out;
    unsigned short* aggS = (unsigned short*)d_ws;                       // 2 MB
    float* aggK = (float*)((char*)d_ws + (size_t)Bc * NC * D * D * 2);  // 32 KB

    void* args[] = {(void*)&Q, (void*)&K, (void*)&V,
                    (void*)&aggS, (void*)&aggK, (void*)&Out};
    hipLaunchCooperativeKernel((const void*)k_fused, dim3(NC, Bc), dim3(512),
                               args, 0, stream);
}

// Round 8
// 77.739 us; speedup vs baseline: 1.7708x; 1.7708x over previous
//
#include <hip/hip_runtime.h>

// Causal linear attention (ELU+1), chunked bf16-MFMA, 3 plain launches.
// R8 = R4 structure + R5/R7's good pieces, no prep pass, no cooperative:
//  k1    (NC,B,2): coalesced reads + swizzled LDS transpose -> S_c^T + ksum
//  k_scan: exclusive chunk prefix, prefetch-all-32 (1 latency wait)
//  k_out (NC,B,4): coalesced staging (V^T via LDS swizzle), MFMA GEMMs,
//                  z folded into MFMA (ones-B rowsum + kprev frags).
// Swizzle: elem (l, row) stored at col ((l>>3 + row>>2)&15)*8 + (l&7);
// read frag (row, kq) at ((kq + row>>2)&15)*8  (verified in R7's k_fused).
// Harness floor ~46us (256MB ws poison fill + input restore); cooperative
// launch adds ~30us replay overhead (R7) — avoided.

#define EPS 1e-6f

constexpr int Bc = 2;
constexpr int L  = 4096;
constexpr int D  = 128;
constexpr int C  = 128;
constexpr int NC = L / C;   // 32
constexpr int P  = 136;     // LDS row pitch (bf16), rows 16B-aligned

typedef short sh8 __attribute__((ext_vector_type(8)));
typedef float f4  __attribute__((ext_vector_type(4)));

__device__ __forceinline__ float phi(float x) {
    return x > 0.0f ? x + 1.0f : __expf(x);
}
__device__ __forceinline__ unsigned short f2bf(float f) {
    unsigned u = __float_as_uint(f);
    return (unsigned short)((u + 0x7FFFu + ((u >> 16) & 1u)) >> 16);  // RNE
}
__device__ __forceinline__ float bf2f(unsigned short h) {
    return __uint_as_float(((unsigned)h) << 16);
}
__device__ __forceinline__ unsigned packbf(float a, float b) {
    return (unsigned)f2bf(a) | ((unsigned)f2bf(b) << 16);
}
__device__ __forceinline__ sh8 splat1() {
    sh8 s;
#pragma unroll
    for (int j = 0; j < 8; ++j) s[j] = (short)0x3F80;
    return s;
}

// ---------------------------------------------------------------------------
// k1 (NC,B,2), 512 thr: S_c^T[v][i] = sum_l V[l][v] phiK[l][i] + ksum.
// vs = v half.  All global reads coalesced; transposes in LDS via swizzle.
// ---------------------------------------------------------------------------
__global__ __launch_bounds__(512) void k1(
    const float* __restrict__ K, const float* __restrict__ V,
    unsigned short* __restrict__ SB, float* __restrict__ Ksum) {
    const int c = blockIdx.x, b = blockIdx.y, vs = blockIdx.z;
    const int tid = threadIdx.x;
    __shared__ __align__(16) unsigned short sVT[64 * P];   // V^T slice [vr][l]
    __shared__ __align__(16) unsigned short sKT[128 * P];  // phiK^T [i][l]
    const size_t base = ((size_t)b * L + (size_t)c * C) * D;

    // V slice: 128 rows x 64 cols f32 = 2048 float4, coalesced
    for (int k = 0; k < 4; ++k) {
        int fi = tid + 512 * k;
        int l = fi >> 4, c4 = fi & 15;      // c4: 16 float4 per row-slice
        float4 vd = *(const float4*)(V + base + (size_t)l * D + vs * 64 + c4 * 4);
        int blk = (((l >> 3) + c4) & 15) * 8 + (l & 7);   // (c4*4+s)>>2 == c4
        sVT[(c4 * 4 + 0) * P + blk] = f2bf(vd.x);
        sVT[(c4 * 4 + 1) * P + blk] = f2bf(vd.y);
        sVT[(c4 * 4 + 2) * P + blk] = f2bf(vd.z);
        sVT[(c4 * 4 + 3) * P + blk] = f2bf(vd.w);
    }
    // K chunk: 128x128 f32 = 4096 float4, coalesced, phi applied
    for (int k = 0; k < 8; ++k) {
        int fi = tid + 512 * k;
        int l = fi >> 5, i4 = fi & 31;
        float4 kd = *(const float4*)(K + base + (size_t)l * D + i4 * 4);
        int blk = (((l >> 3) + i4) & 15) * 8 + (l & 7);
        sKT[(i4 * 4 + 0) * P + blk] = f2bf(phi(kd.x));
        sKT[(i4 * 4 + 1) * P + blk] = f2bf(phi(kd.y));
        sKT[(i4 * 4 + 2) * P + blk] = f2bf(phi(kd.z));
        sKT[(i4 * 4 + 3) * P + blk] = f2bf(phi(kd.w));
    }
    __syncthreads();

    const int w = tid >> 6, lane = tid & 63;
    const int r = lane & 15, q = lane >> 4;
    const int rbase = (w & 3) * 16;        // v rows within 64
    const int cbase = (w >> 2) * 64;       // i cols: w<4 -> 0, w>=4 -> 64
    const bool doK = ((w & 3) == 0);       // waves 0 (i<64) and 4 (i>=64)
    const sh8 ones = splat1();

    f4 acc[4], kz[4];
#pragma unroll
    for (int f = 0; f < 4; ++f) { acc[f] = {0.f,0.f,0.f,0.f}; kz[f] = {0.f,0.f,0.f,0.f}; }
#pragma unroll
    for (int ks = 0; ks < 4; ++ks) {
        int kq = ks * 4 + q;
        int vr = rbase + r;
        sh8 a = *(const sh8*)(sVT + vr * P + ((kq + (vr >> 2)) & 15) * 8);
#pragma unroll
        for (int f = 0; f < 4; ++f) {
            int ir = cbase + f * 16 + r;
            sh8 bk = *(const sh8*)(sKT + ir * P + ((kq + (ir >> 2)) & 15) * 8);
            acc[f] = __builtin_amdgcn_mfma_f32_16x16x32_bf16(a, bk, acc[f], 0, 0, 0);
            if (doK) kz[f] = __builtin_amdgcn_mfma_f32_16x16x32_bf16(ones, bk, kz[f], 0, 0, 0);
        }
    }
    unsigned short* out = SB + ((size_t)(b * NC + c)) * D * D;
#pragma unroll
    for (int f = 0; f < 4; ++f) {
        int i = cbase + f * 16 + r;
#pragma unroll
        for (int e = 0; e < 4; ++e) {
            int v = vs * 64 + rbase + q * 4 + e;
            out[(size_t)v * D + i] = f2bf(acc[f][e]);
        }
    }
    if (doK && q == 0 && vs == 0) {        // colsum rows identical; row 0
#pragma unroll
        for (int f = 0; f < 4; ++f)
            Ksum[((size_t)(b * NC + c)) * D + cbase + f * 16 + r] = kz[f][0];
    }
}

// ---------------------------------------------------------------------------
// k_scan: exclusive prefix over chunks; prefetch all 32 (independent loads,
// one wait) then prefix+store.
// ---------------------------------------------------------------------------
__global__ __launch_bounds__(256) void k_scan(unsigned short* __restrict__ SB,
                                              float* __restrict__ Ksum) {
    const int SD = D * D;
    int idx = blockIdx.x * 256 + threadIdx.x;
    if (idx < Bc * SD) {
        int b = idx / SD, e = idx % SD;
        size_t off0 = (size_t)b * NC * SD + e;
        unsigned short vals[NC];
#pragma unroll
        for (int c = 0; c < NC; ++c) vals[c] = SB[off0 + (size_t)c * SD];
        float run = 0.0f;
#pragma unroll
        for (int c = 0; c < NC; ++c) {
            SB[off0 + (size_t)c * SD] = f2bf(run);
            run += bf2f(vals[c]);
        }
    } else if (idx < Bc * SD + Bc * D) {
        int rr = idx - Bc * SD;
        int b = rr >> 7, i = rr & 127;
        size_t off0 = (size_t)b * NC * D + i;
        float vals[NC];
#pragma unroll
        for (int c = 0; c < NC; ++c) vals[c] = Ksum[off0 + (size_t)c * D];
        float run = 0.0f;
#pragma unroll
        for (int c = 0; c < NC; ++c) {
            Ksum[off0 + (size_t)c * D] = run;
            run += vals[c];
        }
    }
}

// ---------------------------------------------------------------------------
// k_out (NC,B,4), rows split 4x32, 512 thr (8 waves: rbase=(w&1)*16,
// col quarter cq=w>>1).  All staging coalesced; V^T via LDS swizzle;
// S_prev^T reuses sK after GEMM2.  z fully in MFMA.
// ---------------------------------------------------------------------------
__global__ __launch_bounds__(512) void k_out(
    const float* __restrict__ Q, const float* __restrict__ K,
    const float* __restrict__ V, const unsigned short* __restrict__ SB,
    const float* __restrict__ Ksum, float* __restrict__ Out) {
    const int c = blockIdx.x, b = blockIdx.y, rs = blockIdx.z;
    const int tid = threadIdx.x;
    __shared__ __align__(16) unsigned short sQ[32 * P];    // phiQ rows
    __shared__ __align__(16) unsigned short sK[128 * P];   // phiK rows -> S^T
    __shared__ __align__(16) unsigned short sVT[128 * P];  // V^T swizzled
    __shared__ __align__(16) unsigned short sAm[32 * P];   // masked A
    __shared__ float sZ[32];
    const size_t base  = ((size_t)b * L + (size_t)c * C) * D;
    const size_t tbase = ((size_t)(b * NC + c)) * (size_t)D * D;
    const size_t kb    = ((size_t)(b * NC + c)) * D;

    // phiQ slice: 1024 float4
    for (int k = 0; k < 2; ++k) {
        int fi = tid + 512 * k;
        int row = fi >> 5, c4 = fi & 31;
        float4 qd = *(const float4*)(Q + base + (size_t)(rs * 32 + row) * D + c4 * 4);
        uint2 pq; pq.x = packbf(phi(qd.x), phi(qd.y)); pq.y = packbf(phi(qd.z), phi(qd.w));
        *(uint2*)(sQ + row * P + c4 * 4) = pq;
    }
    // phiK rows: 4096 float4, row-major
    for (int k = 0; k < 8; ++k) {
        int fi = tid + 512 * k;
        int row = fi >> 5, c4 = fi & 31;
        float4 kd = *(const float4*)(K + base + (size_t)row * D + c4 * 4);
        uint2 pk; pk.x = packbf(phi(kd.x), phi(kd.y)); pk.y = packbf(phi(kd.z), phi(kd.w));
        *(uint2*)(sK + row * P + c4 * 4) = pk;
    }
    // V^T: 4096 float4 coalesced, swizzled transpose
    for (int k = 0; k < 8; ++k) {
        int fi = tid + 512 * k;
        int l = fi >> 5, i4 = fi & 31;
        float4 vd = *(const float4*)(V + base + (size_t)l * D + i4 * 4);
        int blk = (((l >> 3) + i4) & 15) * 8 + (l & 7);
        sVT[(i4 * 4 + 0) * P + blk] = f2bf(vd.x);
        sVT[(i4 * 4 + 1) * P + blk] = f2bf(vd.y);
        sVT[(i4 * 4 + 2) * P + blk] = f2bf(vd.z);
        sVT[(i4 * 4 + 3) * P + blk] = f2bf(vd.w);
    }
    __syncthreads();                       // S1

    const int w = tid >> 6, lane = tid & 63;
    const int r = lane & 15, q = lane >> 4;
    const int rbase = (w & 1) * 16;
    const int cq = w >> 1, cbase = cq * 32;
    const bool doZ = (cq == 3);            // rows covered by w=6 (rbase 0), w=7 (16)

    // kprev B-frags for GEMM4 z (r-invariant; L2-hot)
    sh8 bzk[4];
    if (doZ) {
#pragma unroll
        for (int ks = 0; ks < 4; ++ks) {
            float4 f0 = *(const float4*)(Ksum + kb + ks * 32 + q * 8);
            float4 f1 = *(const float4*)(Ksum + kb + ks * 32 + q * 8 + 4);
            sh8 t;
            t[0] = (short)f2bf(f0.x); t[1] = (short)f2bf(f0.y);
            t[2] = (short)f2bf(f0.z); t[3] = (short)f2bf(f0.w);
            t[4] = (short)f2bf(f1.x); t[5] = (short)f2bf(f1.y);
            t[6] = (short)f2bf(f1.z); t[7] = (short)f2bf(f1.w);
            bzk[ks] = t;
        }
    }

    // ---- GEMM2: A = phiQ phiK^T ----
    f4 a2[2];
#pragma unroll
    for (int f = 0; f < 2; ++f) a2[f] = {0.f,0.f,0.f,0.f};
#pragma unroll
    for (int ks = 0; ks < 4; ++ks) {
        sh8 a = *(const sh8*)(sQ + (rbase + r) * P + ks * 32 + q * 8);
#pragma unroll
        for (int f = 0; f < 2; ++f) {
            sh8 bb = *(const sh8*)(sK + (cbase + f * 16 + r) * P + ks * 32 + q * 8);
            a2[f] = __builtin_amdgcn_mfma_f32_16x16x32_bf16(a, bb, a2[f], 0, 0, 0);
        }
    }
#pragma unroll
    for (int f = 0; f < 2; ++f) {          // causal mask -> sAm bf16
        int j = cbase + f * 16 + r;
#pragma unroll
        for (int e = 0; e < 4; ++e) {
            int lr = rbase + q * 4 + e;
            sAm[lr * P + j] = f2bf((j <= rs * 32 + lr) ? a2[f][e] : 0.f);
        }
    }
    __syncthreads();                       // S2: sAm ready, sK reads done

    // restage sK <- S_prev^T (row-major bf16, 2048 uint4; overlaps GEMM3)
    {
        const uint4* sg = (const uint4*)(SB + tbase);
        for (int k = 0; k < 4; ++k) {
            int f2 = tid + 512 * k;
            *(uint4*)(sK + (f2 >> 4) * P + (f2 & 15) * 8) = sg[f2];
        }
    }

    // ---- GEMM3: acc = Am @ V (+ rowsum z via ones-B) ----
    f4 acc[2], zacc = {0.f,0.f,0.f,0.f};
#pragma unroll
    for (int f = 0; f < 2; ++f) acc[f] = {0.f,0.f,0.f,0.f};
    const sh8 ones = splat1();
#pragma unroll
    for (int ks = 0; ks < 4; ++ks) {
        int kq = ks * 4 + q;
        sh8 a = *(const sh8*)(sAm + (rbase + r) * P + ks * 32 + q * 8);
#pragma unroll
        for (int f = 0; f < 2; ++f) {
            int vr = cbase + f * 16 + r;
            sh8 bv = *(const sh8*)(sVT + vr * P + ((kq + (vr >> 2)) & 15) * 8);
            acc[f] = __builtin_amdgcn_mfma_f32_16x16x32_bf16(a, bv, acc[f], 0, 0, 0);
        }
        if (doZ) zacc = __builtin_amdgcn_mfma_f32_16x16x32_bf16(a, ones, zacc, 0, 0, 0);
    }
    __syncthreads();                       // S3: sK = S^T ready

    // ---- GEMM4: acc += phiQ @ S_prev (+ kprev z) ----
#pragma unroll
    for (int ks = 0; ks < 4; ++ks) {
        sh8 a = *(const sh8*)(sQ + (rbase + r) * P + ks * 32 + q * 8);
#pragma unroll
        for (int f = 0; f < 2; ++f) {
            sh8 bs = *(const sh8*)(sK + (cbase + f * 16 + r) * P + ks * 32 + q * 8);
            acc[f] = __builtin_amdgcn_mfma_f32_16x16x32_bf16(a, bs, acc[f], 0, 0, 0);
        }
        if (doZ) zacc = __builtin_amdgcn_mfma_f32_16x16x32_bf16(a, bzk[ks], zacc, 0, 0, 0);
    }
    if (doZ && r == 0) {
#pragma unroll
        for (int e = 0; e < 4; ++e) sZ[rbase + q * 4 + e] = zacc[e] + EPS;
    }
    __syncthreads();                       // S4: sZ ready

    // ---- normalize + store ----
#pragma unroll
    for (int f = 0; f < 2; ++f) {
        int v = cbase + f * 16 + r;
#pragma unroll
        for (int e = 0; e < 4; ++e) {
            int lr = rbase + q * 4 + e;
            Out[base + (size_t)(rs * 32 + lr) * D + v] = acc[f][e] / sZ[lr];
        }
    }
}

extern "C" void kernel_launch(void* const* d_in, const int* in_sizes, int n_in,
                              void* d_out, int out_size, void* d_ws, size_t ws_size,
                              hipStream_t stream) {
    const float* Q = (const float*)d_in[0];
    const float* K = (const float*)d_in[1];
    const float* V = (const float*)d_in[2];
    float* Out = (float*)d_out;
    unsigned short* SBw = (unsigned short*)d_ws;                        // 2 MB
    float* Ksum = (float*)((char*)d_ws + (size_t)Bc * NC * D * D * 2);  // 32 KB

    k1<<<dim3(NC, Bc, 2), 512, 0, stream>>>(K, V, SBw, Ksum);
    int total = Bc * D * D + Bc * D;
    k_scan<<<dim3((total + 255) / 256), 256, 0, stream>>>(SBw, Ksum);
    k_out<<<dim3(NC, Bc, 4), 512, 0, stream>>>(Q, K, V, SBw, Ksum, Out);
}